// Round 1
// 1828.052 us; speedup vs baseline: 1.3104x; 1.3104x over previous
//
#include <hip/hip_runtime.h>
#include <math.h>

#define BB 16
#define TT 12
#define NN 1024
#define FF 8
#define HH 64
#define EE 32768
#define DIN 320   // H * (2K+1)
#define ODIM 96   // F * HORIZON
#define FS 512    // feats cols: [Af|Af2|Ab|Ab2] x [x(64)|h(64)]
#define APAD 40   // k_msq LDS row stride

typedef _Float16 v8h __attribute__((ext_vector_type(8)));
typedef float v4f __attribute__((ext_vector_type(4)));

__device__ __forceinline__ unsigned short f2h(float v) {
    _Float16 h = (_Float16)v;          // RNE v_cvt_f16_f32
    unsigned short u;
    __builtin_memcpy(&u, &h, 2);
    return u;
}
// async global->LDS, 16B per lane; LDS dst = wave-uniform base + lane*16
__device__ __forceinline__ void gl_lds16(const void* g, void* l) {
    __builtin_amdgcn_global_load_lds(
        (const __attribute__((address_space(1))) unsigned int*)g,
        (__attribute__((address_space(3))) unsigned int*)l, 16, 0, 0);
}

// ---------------- edge_index insurance ----------------
__global__ void k_ei_detect(const int* __restrict__ ei_raw, int* __restrict__ flag) {
    __shared__ int s[256];
    s[threadIdx.x] = ei_raw[2 * threadIdx.x + 1];
    __syncthreads();
    for (int st = 128; st > 0; st >>= 1) {
        if (threadIdx.x < st) s[threadIdx.x] |= s[threadIdx.x + st];
        __syncthreads();
    }
    if (threadIdx.x == 0) flag[0] = (s[0] == 0) ? 1 : 0;
}
__global__ void k_ei_norm(const int* __restrict__ ei_raw, const int* __restrict__ flag,
                          int* __restrict__ ei32) {
    int j = blockIdx.x * 256 + threadIdx.x;
    ei32[j] = flag[0] ? ei_raw[2 * j] : ei_raw[j];
}

// ---------------- support normalization ----------------
__global__ void k_rowsum(const float* __restrict__ adj, float* __restrict__ rinv) {
    __shared__ float s[256];
    int i = blockIdx.x;
    float acc = 0.f;
    for (int j = threadIdx.x; j < NN; j += 256) acc += adj[i * NN + j];
    s[threadIdx.x] = acc;
    __syncthreads();
    for (int st = 128; st > 0; st >>= 1) {
        if (threadIdx.x < st) s[threadIdx.x] += s[threadIdx.x + st];
        __syncthreads();
    }
    if (threadIdx.x == 0) rinv[i] = (s[0] != 0.f) ? 1.f / s[0] : 0.f;
}
__global__ void k_colsum(const float* __restrict__ adj, float* __restrict__ cinv) {
    int j = blockIdx.x * 256 + threadIdx.x;
    float acc = 0.f;
    for (int i = 0; i < NN; i++) acc += adj[i * NN + j];
    cinv[j] = (acc != 0.f) ? 1.f / acc : 0.f;
}

// ---------------- Af -> plain rows 0..1023, Ab -> plain rows 2048..3071 (single fp16) ----------------
__global__ __launch_bounds__(256) void k_prepA(
        const float* __restrict__ adj, const float* __restrict__ rinv,
        const float* __restrict__ cinv, unsigned short* __restrict__ Mp) {
    int w0 = blockIdx.x * 64, v0 = blockIdx.y * 64;
    __shared__ float T[64][68];
    int row = threadIdx.x >> 2, cs = (threadIdx.x & 3) * 16;
    #pragma unroll
    for (int j = 0; j < 4; j++)
        *(float4*)&T[row][cs + j * 4] = *(const float4*)(adj + (size_t)(w0 + row) * NN + v0 + cs + j * 4);
    __syncthreads();
    {
        float sc = rinv[w0 + row];
        unsigned short h8[16];
        #pragma unroll
        for (int j = 0; j < 16; j++) h8[j] = f2h(T[row][cs + j] * sc);
        size_t ofs = (size_t)(w0 + row) * NN + v0 + cs;
        ((uint4*)(Mp + ofs))[0] = *(uint4*)&h8[0];
        ((uint4*)(Mp + ofs))[1] = *(uint4*)&h8[8];
    }
    {
        float sc = cinv[v0 + row];
        unsigned short h8[16];
        #pragma unroll
        for (int j = 0; j < 16; j++) h8[j] = f2h(T[cs + j][row] * sc);
        size_t ofs = (size_t)2048 * NN + (size_t)(v0 + row) * NN + w0 + cs;
        ((uint4*)(Mp + ofs))[0] = *(uint4*)&h8[0];
        ((uint4*)(Mp + ofs))[1] = *(uint4*)&h8[8];
    }
}

// ---------------- plain M rows (zz) squared: rows zz*2048 -> zz*2048+1024 ----------------
__global__ __launch_bounds__(256) void k_msq(unsigned short* __restrict__ M) {
    int zz = blockIdx.z;
    size_t srcb = (size_t)zz * 2048 * NN;
    size_t dstb = srcb + (size_t)1024 * NN;
    int w0 = blockIdx.x * 64, n0 = blockIdx.y * 64;

    __shared__ unsigned short sA[64 * APAD];
    __shared__ unsigned short sB[64 * APAD];

    int tid = threadIdx.x;
    int lane = tid & 63, wave = tid >> 6;
    int wr = (wave >> 1) * 32, wc = (wave & 1) * 32;
    int l15 = lane & 15, quad = lane >> 4;
    int arow = tid >> 2, akk = (tid & 3) * 8;
    int bkr = tid & 31, bc8 = (tid >> 5) * 8;

    v4f acc[2][2];
    #pragma unroll
    for (int i = 0; i < 2; i++)
        #pragma unroll
        for (int j = 0; j < 2; j++) { acc[i][j][0]=0.f; acc[i][j][1]=0.f; acc[i][j][2]=0.f; acc[i][j][3]=0.f; }

    for (int k0 = 0; k0 < NN; k0 += 32) {
        *(uint4*)&sA[arow * APAD + akk] = *(const uint4*)(M + srcb + (size_t)(w0 + arow) * NN + k0 + akk);
        uint4 bh = *(const uint4*)(M + srcb + (size_t)(k0 + bkr) * NN + n0 + bc8);
        const unsigned short* ph = (const unsigned short*)&bh;
        #pragma unroll
        for (int j = 0; j < 8; j++) sB[(bc8 + j) * APAD + bkr] = ph[j];
        __syncthreads();

        v8h a0 = *(const v8h*)&sA[(wr + l15) * APAD + quad * 8];
        v8h a1 = *(const v8h*)&sA[(wr + 16 + l15) * APAD + quad * 8];
        #pragma unroll
        for (int j = 0; j < 2; j++) {
            v8h bb = *(const v8h*)&sB[(wc + j * 16 + l15) * APAD + quad * 8];
            acc[0][j] = __builtin_amdgcn_mfma_f32_16x16x32_f16(a0, bb, acc[0][j], 0, 0, 0);
            acc[1][j] = __builtin_amdgcn_mfma_f32_16x16x32_f16(a1, bb, acc[1][j], 0, 0, 0);
        }
        __syncthreads();
    }

    #pragma unroll
    for (int i = 0; i < 2; i++)
        #pragma unroll
        for (int j = 0; j < 2; j++) {
            int rb = w0 + wr + i * 16 + quad * 4;
            int cc = n0 + wc + j * 16 + l15;
            #pragma unroll
            for (int rr = 0; rr < 4; rr++)
                M[dstb + (size_t)(rb + rr) * NN + cc] = f2h(acc[i][j][rr]);
        }
}

// ---------------- plain -> fragment-major: chunk t = (T*128 + kc)*64 + rowloc ----------------
__global__ void k_m2frag(const unsigned short* __restrict__ P, unsigned short* __restrict__ F) {
    size_t t = (size_t)blockIdx.x * 256 + threadIdx.x;
    int rowloc = (int)(t & 63);
    int kc = (int)((t >> 6) & 127);
    int T = (int)(t >> 13);
    size_t src = ((size_t)(T * 64 + rowloc) * NN) + kc * 8;
    *(uint4*)(F + t * 8) = *(const uint4*)(P + src);
}

// ---------------- encoder -> XT x-cols (transposed, single fp16): XT[b][c][n] ----------------
__global__ void k_encT(const float* __restrict__ x, const float* __restrict__ W_enc,
                       const float* __restrict__ b_enc, const float* __restrict__ emb,
                       unsigned short* __restrict__ XT, int t) {
    int b = blockIdx.x >> 6;
    int c = blockIdx.x & 63;
    int n8 = threadIdx.x * 8;
    float w[FF];
    #pragma unroll
    for (int f = 0; f < FF; f++) w[f] = W_enc[f * HH + c];
    float be = b_enc[c];
    unsigned short h8[8];
    #pragma unroll
    for (int j = 0; j < 8; j++) {
        int n = n8 + j;
        const float* xr = x + (((size_t)b * TT + t) * NN + n) * FF;
        float acc = be + emb[(size_t)n * HH + c];
        #pragma unroll
        for (int f = 0; f < FF; f++) acc += xr[f] * w[f];
        h8[j] = f2h(acc);
    }
    size_t o = ((size_t)b * 128 + c) * NN + n8;
    *(uint4*)(XT + o) = *(uint4*)h8;
}

// ---------------- async-LDS stacked hop, single fp16, BK=64 ----------------
// M fragment-major, XT [c][n]. Block 128 rows x 64 cols, 4 waves (64x32 each).
// Staging: 24 x 1KB global_load_lds(16B) segments per K-tile of 64, lane-ordered LDS.
__global__ __launch_bounds__(256) void k_hopA(
        const unsigned short* __restrict__ Mf,
        const unsigned short* __restrict__ XT,
        int in_off,
        float* __restrict__ Yout, int out_stride, int out_gmul, int out_off) {
    int rt = blockIdx.x;
    int g = rt >> 3;
    int n0 = (rt & 7) * 128;
    int b = blockIdx.z;
    int c0 = in_off + blockIdx.y * 64;

    __shared__ unsigned short sA[16 * 512];   // [ah2][kh2][rf4] x 1KB : 128 rows x 64 K
    __shared__ unsigned short sX[8 * 512];    // [cj4][kh2] x 1KB : 64 cols x 64 K

    int tid = threadIdx.x;
    int lane = tid & 63, wave = tid >> 6;
    int half = wave >> 1;           // A row-half this wave consumes
    int ch_ = (wave & 1) * 32;
    int l15 = lane & 15, quad = lane >> 4;

    const unsigned short* Xb = XT + (size_t)b * 128 * NN;

    v4f acc[4][2];
    #pragma unroll
    for (int i = 0; i < 4; i++)
        #pragma unroll
        for (int j = 0; j < 2; j++) { acc[i][j][0]=0.f; acc[i][j][1]=0.f; acc[i][j][2]=0.f; acc[i][j][3]=0.f; }

    for (int k0 = 0; k0 < NN; k0 += 64) {
        // issue this wave's 6 segments (ids: wave, wave+4, ..., wave+20)
        #pragma unroll
        for (int s = 0; s < 6; s++) {
            int id = wave + s * 4;
            if (id < 16) {
                int ah = id >> 3, kh = (id >> 2) & 1, rf = id & 3;
                const unsigned short* src = Mf +
                    ((size_t)(rt * 2 + ah) * 8192 +
                     (size_t)((k0 >> 3) + kh * 4 + quad) * 64 + rf * 16 + l15) * 8;
                gl_lds16(src, &sA[id * 512]);
            } else {
                int xi = id - 16, cj = xi >> 1, kh = xi & 1;
                const unsigned short* src = Xb +
                    (size_t)(c0 + cj * 16 + l15) * NN + k0 + kh * 32 + quad * 8;
                gl_lds16(src, &sX[xi * 512]);
            }
        }
        __syncthreads();   // drains vmcnt -> staged data visible

        int lu = lane * 8;   // lane*16B in ushorts
        #pragma unroll
        for (int kh = 0; kh < 2; kh++) {
            v8h a[4], bx[2];
            #pragma unroll
            for (int rf = 0; rf < 4; rf++)
                a[rf] = *(const v8h*)&sA[(half * 8 + kh * 4 + rf) * 512 + lu];
            #pragma unroll
            for (int j = 0; j < 2; j++) {
                int cj = (wave & 1) * 2 + j;
                bx[j] = *(const v8h*)&sX[(cj * 2 + kh) * 512 + lu];
            }
            #pragma unroll
            for (int rf = 0; rf < 4; rf++)
                #pragma unroll
                for (int j = 0; j < 2; j++)
                    acc[rf][j] = __builtin_amdgcn_mfma_f32_16x16x32_f16(a[rf], bx[j], acc[rf][j], 0, 0, 0);
        }
        __syncthreads();   // all reads done before next overwrite
    }

    float* Y = Yout + (size_t)b * NN * out_stride + out_gmul * g + out_off + blockIdx.y * 64 + ch_;
    #pragma unroll
    for (int rf = 0; rf < 4; rf++)
        #pragma unroll
        for (int j = 0; j < 2; j++) {
            int rbase = n0 + half * 64 + rf * 16 + quad * 4;
            int cc = j * 16 + l15;
            #pragma unroll
            for (int rr = 0; rr < 4; rr++)
                Y[(size_t)(rbase + rr) * out_stride + cc] = acc[rf][j][rr];
        }
}

// ---------------- gates: r,u = sigmoid(feats@W+b); rh -> XT h-cols (fp16), u -> f32 ubuf ----------------
__global__ __launch_bounds__(256) void k_gates(
        const float* __restrict__ feats,
        const float* __restrict__ W_r, const float* __restrict__ W_u,
        const float* __restrict__ b_r, const float* __restrict__ b_u,
        const float* __restrict__ h,
        unsigned short* __restrict__ XT, float* __restrict__ ubuf) {
    int row0 = blockIdx.x * 32;
    int b = row0 >> 10, n0g = row0 & 1023;
    __shared__ float Fa[16][36];
    __shared__ float Wr[16][68];
    __shared__ float Wu[16][68];
    __shared__ float sTr[64][33];

    int tid = threadIdx.x;
    int ar = tid >> 3,  ak2 = (tid & 7) * 2;
    int bk = tid >> 4,  bc4 = (tid & 15) * 4;
    int ty = tid >> 4,  tx  = tid & 15;

    float accr[2][4] = {}, accu[2][4] = {};
    for (int k0 = 0; k0 < FS; k0 += 16) {
        float2 fv = *(const float2*)(feats + (size_t)(row0 + ar) * FS + k0 + ak2);
        Fa[ak2 + 0][ar] = fv.x; Fa[ak2 + 1][ar] = fv.y;
        *(float4*)&Wr[bk][bc4] = *(const float4*)(W_r + (size_t)(k0 + bk) * HH + bc4);
        *(float4*)&Wu[bk][bc4] = *(const float4*)(W_u + (size_t)(k0 + bk) * HH + bc4);
        __syncthreads();
        #pragma unroll
        for (int kk = 0; kk < 16; kk++) {
            float a0 = Fa[kk][ty * 2 + 0];
            float a1 = Fa[kk][ty * 2 + 1];
            const float4 r4 = *(const float4*)&Wr[kk][tx * 4];
            const float4 u4 = *(const float4*)&Wu[kk][tx * 4];
            accr[0][0] += a0 * r4.x; accr[0][1] += a0 * r4.y; accr[0][2] += a0 * r4.z; accr[0][3] += a0 * r4.w;
            accr[1][0] += a1 * r4.x; accr[1][1] += a1 * r4.y; accr[1][2] += a1 * r4.z; accr[1][3] += a1 * r4.w;
            accu[0][0] += a0 * u4.x; accu[0][1] += a0 * u4.y; accu[0][2] += a0 * u4.z; accu[0][3] += a0 * u4.w;
            accu[1][0] += a1 * u4.x; accu[1][1] += a1 * u4.y; accu[1][2] += a1 * u4.z; accu[1][3] += a1 * u4.w;
        }
        __syncthreads();
    }
    #pragma unroll
    for (int i = 0; i < 2; i++) {
        int nloc = ty * 2 + i;
        size_t row = row0 + nloc;
        float uv[4];
        #pragma unroll
        for (int j = 0; j < 4; j++) {
            int c = tx * 4 + j;
            float r = 1.f / (1.f + expf(-(accr[i][j] + b_r[c])));
            float u = 1.f / (1.f + expf(-(accu[i][j] + b_u[c])));
            sTr[c][nloc] = r * h[row * HH + c];
            uv[j] = u;
        }
        *(float4*)&ubuf[row * HH + tx * 4] = *(float4*)uv;   // u stays exact f32
    }
    __syncthreads();
    int c2 = tid >> 2, n8 = (tid & 3) * 8;
    unsigned short h8[8];
    #pragma unroll
    for (int j = 0; j < 8; j++) h8[j] = f2h(sTr[c2][n8 + j]);
    size_t oh = ((size_t)b * 128 + 64 + c2) * NN + n0g + n8;
    *(uint4*)(XT + oh) = *(uint4*)h8;
}

// ---------------- candidate + h update; new h -> h f32 AND XT h-cols (fp16) ----------------
__global__ __launch_bounds__(256) void k_cand(
        const float* __restrict__ feats, const float* __restrict__ W_c,
        const float* __restrict__ b_c,
        const float* __restrict__ ubuf,
        float* __restrict__ h, unsigned short* __restrict__ XT) {
    int row0 = blockIdx.x * 32;
    int b = row0 >> 10, n0g = row0 & 1023;
    __shared__ float Fa[16][36];
    __shared__ float Wb[16][68];
    __shared__ float sT[64][33];

    int tid = threadIdx.x;
    int ar = tid >> 3,  ak2 = (tid & 7) * 2;
    int bk = tid >> 4,  bc4 = (tid & 15) * 4;
    int ty = tid >> 4,  tx  = tid & 15;

    float acc[2][4] = {};
    for (int k0 = 0; k0 < FS; k0 += 16) {
        float2 fv = *(const float2*)(feats + (size_t)(row0 + ar) * FS + k0 + ak2);
        Fa[ak2 + 0][ar] = fv.x; Fa[ak2 + 1][ar] = fv.y;
        *(float4*)&Wb[bk][bc4] = *(const float4*)(W_c + (size_t)(k0 + bk) * HH + bc4);
        __syncthreads();
        #pragma unroll
        for (int kk = 0; kk < 16; kk++) {
            float a0 = Fa[kk][ty * 2 + 0];
            float a1 = Fa[kk][ty * 2 + 1];
            const float4 b4 = *(const float4*)&Wb[kk][tx * 4];
            acc[0][0] += a0 * b4.x; acc[0][1] += a0 * b4.y; acc[0][2] += a0 * b4.z; acc[0][3] += a0 * b4.w;
            acc[1][0] += a1 * b4.x; acc[1][1] += a1 * b4.y; acc[1][2] += a1 * b4.z; acc[1][3] += a1 * b4.w;
        }
        __syncthreads();
    }
    #pragma unroll
    for (int i = 0; i < 2; i++) {
        int nloc = ty * 2 + i;
        size_t row = row0 + nloc;
        float4 u4 = *(const float4*)&ubuf[row * HH + tx * 4];
        float uu[4] = {u4.x, u4.y, u4.z, u4.w};
        #pragma unroll
        for (int j = 0; j < 4; j++) {
            int c = tx * 4 + j;
            float cv = tanhf(acc[i][j] + b_c[c]);
            float u = uu[j];
            float hv = h[row * HH + c];
            float hn = u * hv + (1.f - u) * cv;
            h[row * HH + c] = hn;
            sT[c][nloc] = hn;
        }
    }
    __syncthreads();
    int c2 = tid >> 2, n8 = (tid & 3) * 8;
    unsigned short h8[8];
    #pragma unroll
    for (int j = 0; j < 8; j++) h8[j] = f2h(sT[c2][n8 + j]);
    size_t oh = ((size_t)b * 128 + 64 + c2) * NN + n0g + n8;
    *(uint4*)(XT + oh) = *(uint4*)h8;
}

// ---------------- DiffConv operator build ----------------
__global__ void k_deg(const int* __restrict__ ei32, const float* __restrict__ ew,
                      float* __restrict__ degd, float* __restrict__ degs) {
    int e = blockIdx.x * 256 + threadIdx.x;
    float w = ew[e];
    atomicAdd(&degd[ei32[EE + e]], w);
    atomicAdd(&degs[ei32[e]], w);
}
__global__ void k_spadd(const int* __restrict__ ei32, const float* __restrict__ ew,
                        const float* __restrict__ degd, const float* __restrict__ degs,
                        float* __restrict__ temp) {
    int e = blockIdx.x * 256 + threadIdx.x;
    int s = ei32[e], d = ei32[EE + e];
    float w = ew[e];
    float dd = degd[d], ds = degs[s];
    float wfv = dd > 0.f ? w / dd : 0.f;
    float wbv = ds > 0.f ? w / ds : 0.f;
    atomicAdd(&temp[(size_t)d * NN + s], wfv);
    atomicAdd(&temp[(size_t)NN * NN + (size_t)s * NN + d], wbv);
}
__global__ void k_spconv(const float* __restrict__ temp, unsigned short* __restrict__ Mp) {
    size_t i0 = ((size_t)blockIdx.x * 256 + threadIdx.x) * 8;
    size_t dst = (i0 < (size_t)NN * NN) ? i0 : i0 + (size_t)NN * NN;
    unsigned short h8[8];
    #pragma unroll
    for (int j = 0; j < 8; j++) h8[j] = f2h(temp[i0 + j]);
    *(uint4*)(Mp + dst) = *(uint4*)h8;
}

__global__ void k_featd_h(const float* __restrict__ h, float* __restrict__ featd) {
    size_t idx = (size_t)blockIdx.x * 256 + threadIdx.x;
    size_t row = idx >> 6; int c = (int)(idx & 63);
    featd[row * DIN + c] = h[idx];
}

__global__ __launch_bounds__(256) void k_z(
        const float* __restrict__ featd, const float* __restrict__ W_diff,
        const float* __restrict__ b_diff, float* __restrict__ z) {
    int row0 = blockIdx.x * 4;
    __shared__ float sF[4 * DIN];
    int tid = threadIdx.x;
    for (int i = tid; i < 4 * DIN / 4; i += 256)
        *(float4*)&sF[i * 4] = *(const float4*)&featd[(size_t)row0 * DIN + (size_t)i * 4];
    __syncthreads();
    int lr = tid >> 6, ch = tid & 63;
    const float* f = &sF[lr * DIN];
    float acc = b_diff[ch];
    for (int k = 0; k < DIN; k++) acc += f[k] * W_diff[k * HH + ch];
    z[(size_t)(row0 + lr) * HH + ch] = acc;
}

__global__ void k_dec(const float* __restrict__ z, const float* __restrict__ W_dec,
                      const float* __restrict__ b_dec, float* __restrict__ out) {
    size_t idx = (size_t)blockIdx.x * 256 + threadIdx.x;
    size_t row = idx / ODIM; int o = (int)(idx % ODIM);
    const float* zr = z + row * HH;
    float acc = b_dec[o];
    for (int k = 0; k < HH; k++) acc += zr[k] * W_dec[k * ODIM + o];
    int b = (int)(row >> 10), n = (int)(row & 1023);
    int t = o >> 3, f = o & 7;
    out[(((size_t)b * TT + t) * NN + n) * FF + f] = acc;
}

extern "C" void kernel_launch(void* const* d_in, const int* in_sizes, int n_in,
                              void* d_out, int out_size, void* d_ws, size_t ws_size,
                              hipStream_t stream) {
    const float* x      = (const float*)d_in[0];
    const int*   eiraw  = (const int*)  d_in[1];
    const float* ew     = (const float*)d_in[2];
    const float* adj    = (const float*)d_in[3];
    const float* W_enc  = (const float*)d_in[4];
    const float* b_enc  = (const float*)d_in[5];
    const float* emb    = (const float*)d_in[6];
    const float* W_r    = (const float*)d_in[7];
    const float* b_r    = (const float*)d_in[8];
    const float* W_u    = (const float*)d_in[9];
    const float* b_u    = (const float*)d_in[10];
    const float* W_c    = (const float*)d_in[11];
    const float* b_c    = (const float*)d_in[12];
    const float* W_diff = (const float*)d_in[13];
    const float* b_diff = (const float*)d_in[14];
    const float* W_dec  = (const float*)d_in[15];
    const float* b_dec  = (const float*)d_in[16];

    // ---- workspace: 52 MiB ----
    unsigned short* Mf = (unsigned short*)d_ws;           // frag fp16 8 MiB
    unsigned short* XT = Mf + (size_t)4096 * NN;          // fp16 4 MiB
    float* feats = (float*)(XT + (size_t)BB * 128 * NN);  // 32 MiB
    float* h     = feats + (size_t)BB * NN * FS;          // 4 MiB
    float* ubuf  = h + (size_t)BB * NN * HH;              // 4 MiB
    // overlays inside feats:
    unsigned short* Mp = (unsigned short*)feats;          // plain fp16 8 MiB
    float* sptmp = feats + (size_t)4 * 1024 * 1024;       // 8 MiB @ +16 MiB
    float* rinv  = feats + (size_t)6 * 1024 * 1024;
    float* cinv  = rinv + NN;
    int*   eifl  = (int*)(cinv + NN);
    int*   ei32  = eifl + 4;
    float* degd  = (float*)(ei32 + 2 * EE);
    float* degs  = degd + NN;
    float* featd = feats;
    float* z     = h;

    hipMemsetAsync(h, 0, (size_t)BB * NN * HH * 4, stream);

    // ---- build plain M = [Af; Af^2; Ab; Ab^2] (fp16), convert to fragment-major ----
    k_rowsum<<<NN, 256, 0, stream>>>(adj, rinv);
    k_colsum<<<NN / 256, 256, 0, stream>>>(adj, cinv);
    k_prepA<<<dim3(16, 16), 256, 0, stream>>>(adj, rinv, cinv, Mp);
    k_msq<<<dim3(16, 16, 2), 256, 0, stream>>>(Mp);
    k_m2frag<<<2048, 256, 0, stream>>>(Mp, Mf);
    hipMemsetAsync(XT, 0, (size_t)BB * 128 * NN * 2, stream);  // h-cols = 0 at t=0

    for (int t = 0; t < TT; t++) {
        k_encT<<<BB * 64, 128, 0, stream>>>(x, W_enc, b_enc, emb, XT, t);
        // 4 operators x [x|h] -> feats cols g*128 + 0..127
        k_hopA<<<dim3(32, 2, 16), 256, 0, stream>>>(Mf, XT, 0, feats, FS, 128, 0);
        // gates: rh -> XT h-cols (fp16), u -> ubuf (f32)
        k_gates<<<BB * NN / 32, 256, 0, stream>>>(feats, W_r, W_u, b_r, b_u, h, XT, ubuf);
        // 4 operators @ rh -> feats h-cols
        k_hopA<<<dim3(32, 1, 16), 256, 0, stream>>>(Mf, XT, 64, feats, FS, 128, 64);
        // candidate + h update
        k_cand<<<BB * NN / 32, 256, 0, stream>>>(feats, W_c, b_c, ubuf, h, XT);
    }

    // ---- DiffConv readout ----
    k_ei_detect<<<1, 256, 0, stream>>>(eiraw, eifl);
    k_ei_norm<<<2 * EE / 256, 256, 0, stream>>>(eiraw, eifl, ei32);
    hipMemsetAsync(degd, 0, (size_t)2 * NN * 4, stream);
    hipMemsetAsync(sptmp, 0, (size_t)2 * NN * NN * 4, stream);
    k_deg<<<EE / 256, 256, 0, stream>>>(ei32, ew, degd, degs);
    k_spadd<<<EE / 256, 256, 0, stream>>>(ei32, ew, degd, degs, sptmp);
    k_spconv<<<2 * NN * NN / (256 * 8), 256, 0, stream>>>(sptmp, Mp);
    k_msq<<<dim3(16, 16, 2), 256, 0, stream>>>(Mp);
    k_m2frag<<<2048, 256, 0, stream>>>(Mp, Mf);
    k_featd_h<<<BB * NN * HH / 256, 256, 0, stream>>>(h, featd);
    // [Sf;Sf2;Sb;Sb2] @ h (hT in XT h-cols) -> featd cols 64 + g*64
    k_hopA<<<dim3(32, 1, 16), 256, 0, stream>>>(Mf, XT, 64, featd, DIN, 64, 64);
    k_z<<<BB * NN / 4, 256, 0, stream>>>(featd, W_diff, b_diff, z);
    k_dec<<<(BB * NN * ODIM) / 256, 256, 0, stream>>>(z, W_dec, b_dec, (float*)d_out);
}

// Round 2
// 1306.797 us; speedup vs baseline: 1.8331x; 1.3989x over previous
//
#include <hip/hip_runtime.h>
#include <math.h>

#define BB 16
#define TT 12
#define NN 1024
#define FF 8
#define HH 64
#define EE 32768
#define DIN 320   // H * (2K+1)
#define ODIM 96   // F * HORIZON
#define FS 512    // feats cols: [Af|Af2|Ab|Ab2] x [x(64)|h(64)]
#define APAD 40   // k_msq LDS row stride

typedef _Float16 v8h __attribute__((ext_vector_type(8)));
typedef float v4f __attribute__((ext_vector_type(4)));

__device__ __forceinline__ unsigned short f2h(float v) {
    _Float16 h = (_Float16)v;          // RNE v_cvt_f16_f32
    unsigned short u;
    __builtin_memcpy(&u, &h, 2);
    return u;
}
__device__ __forceinline__ float h2f(unsigned short u) {
    _Float16 h;
    __builtin_memcpy(&h, &u, 2);
    return (float)h;
}
// async global->LDS, 16B per lane; LDS dst = wave-uniform base + lane*16
__device__ __forceinline__ void gl_lds16(const void* g, void* l) {
    __builtin_amdgcn_global_load_lds(
        (const __attribute__((address_space(1))) unsigned int*)g,
        (__attribute__((address_space(3))) unsigned int*)l, 16, 0, 0);
}

// ---------------- edge_index insurance ----------------
__global__ void k_ei_detect(const int* __restrict__ ei_raw, int* __restrict__ flag) {
    __shared__ int s[256];
    s[threadIdx.x] = ei_raw[2 * threadIdx.x + 1];
    __syncthreads();
    for (int st = 128; st > 0; st >>= 1) {
        if (threadIdx.x < st) s[threadIdx.x] |= s[threadIdx.x + st];
        __syncthreads();
    }
    if (threadIdx.x == 0) flag[0] = (s[0] == 0) ? 1 : 0;
}
__global__ void k_ei_norm(const int* __restrict__ ei_raw, const int* __restrict__ flag,
                          int* __restrict__ ei32) {
    int j = blockIdx.x * 256 + threadIdx.x;
    ei32[j] = flag[0] ? ei_raw[2 * j] : ei_raw[j];
}

// ---------------- support normalization ----------------
__global__ void k_rowsum(const float* __restrict__ adj, float* __restrict__ rinv) {
    __shared__ float s[256];
    int i = blockIdx.x;
    float acc = 0.f;
    for (int j = threadIdx.x; j < NN; j += 256) acc += adj[i * NN + j];
    s[threadIdx.x] = acc;
    __syncthreads();
    for (int st = 128; st > 0; st >>= 1) {
        if (threadIdx.x < st) s[threadIdx.x] += s[threadIdx.x + st];
        __syncthreads();
    }
    if (threadIdx.x == 0) rinv[i] = (s[0] != 0.f) ? 1.f / s[0] : 0.f;
}
__global__ void k_colsum(const float* __restrict__ adj, float* __restrict__ cinv) {
    int j = blockIdx.x * 256 + threadIdx.x;
    float acc = 0.f;
    for (int i = 0; i < NN; i++) acc += adj[i * NN + j];
    cinv[j] = (acc != 0.f) ? 1.f / acc : 0.f;
}

// ---------------- Af -> plain rows 0..1023, Ab -> plain rows 2048..3071 (single fp16) ----------------
__global__ __launch_bounds__(256) void k_prepA(
        const float* __restrict__ adj, const float* __restrict__ rinv,
        const float* __restrict__ cinv, unsigned short* __restrict__ Mp) {
    int w0 = blockIdx.x * 64, v0 = blockIdx.y * 64;
    __shared__ float T[64][68];
    int row = threadIdx.x >> 2, cs = (threadIdx.x & 3) * 16;
    #pragma unroll
    for (int j = 0; j < 4; j++)
        *(float4*)&T[row][cs + j * 4] = *(const float4*)(adj + (size_t)(w0 + row) * NN + v0 + cs + j * 4);
    __syncthreads();
    {
        float sc = rinv[w0 + row];
        unsigned short h8[16];
        #pragma unroll
        for (int j = 0; j < 16; j++) h8[j] = f2h(T[row][cs + j] * sc);
        size_t ofs = (size_t)(w0 + row) * NN + v0 + cs;
        ((uint4*)(Mp + ofs))[0] = *(uint4*)&h8[0];
        ((uint4*)(Mp + ofs))[1] = *(uint4*)&h8[8];
    }
    {
        float sc = cinv[v0 + row];
        unsigned short h8[16];
        #pragma unroll
        for (int j = 0; j < 16; j++) h8[j] = f2h(T[cs + j][row] * sc);
        size_t ofs = (size_t)2048 * NN + (size_t)(v0 + row) * NN + w0 + cs;
        ((uint4*)(Mp + ofs))[0] = *(uint4*)&h8[0];
        ((uint4*)(Mp + ofs))[1] = *(uint4*)&h8[8];
    }
}

// ---------------- plain M rows (zz) squared: rows zz*2048 -> zz*2048+1024 ----------------
__global__ __launch_bounds__(256) void k_msq(unsigned short* __restrict__ M) {
    int zz = blockIdx.z;
    size_t srcb = (size_t)zz * 2048 * NN;
    size_t dstb = srcb + (size_t)1024 * NN;
    int w0 = blockIdx.x * 64, n0 = blockIdx.y * 64;

    __shared__ unsigned short sA[64 * APAD];
    __shared__ unsigned short sB[64 * APAD];

    int tid = threadIdx.x;
    int lane = tid & 63, wave = tid >> 6;
    int wr = (wave >> 1) * 32, wc = (wave & 1) * 32;
    int l15 = lane & 15, quad = lane >> 4;
    int arow = tid >> 2, akk = (tid & 3) * 8;
    int bkr = tid & 31, bc8 = (tid >> 5) * 8;

    v4f acc[2][2];
    #pragma unroll
    for (int i = 0; i < 2; i++)
        #pragma unroll
        for (int j = 0; j < 2; j++) { acc[i][j][0]=0.f; acc[i][j][1]=0.f; acc[i][j][2]=0.f; acc[i][j][3]=0.f; }

    for (int k0 = 0; k0 < NN; k0 += 32) {
        *(uint4*)&sA[arow * APAD + akk] = *(const uint4*)(M + srcb + (size_t)(w0 + arow) * NN + k0 + akk);
        uint4 bh = *(const uint4*)(M + srcb + (size_t)(k0 + bkr) * NN + n0 + bc8);
        const unsigned short* ph = (const unsigned short*)&bh;
        #pragma unroll
        for (int j = 0; j < 8; j++) sB[(bc8 + j) * APAD + bkr] = ph[j];
        __syncthreads();

        v8h a0 = *(const v8h*)&sA[(wr + l15) * APAD + quad * 8];
        v8h a1 = *(const v8h*)&sA[(wr + 16 + l15) * APAD + quad * 8];
        #pragma unroll
        for (int j = 0; j < 2; j++) {
            v8h bb = *(const v8h*)&sB[(wc + j * 16 + l15) * APAD + quad * 8];
            acc[0][j] = __builtin_amdgcn_mfma_f32_16x16x32_f16(a0, bb, acc[0][j], 0, 0, 0);
            acc[1][j] = __builtin_amdgcn_mfma_f32_16x16x32_f16(a1, bb, acc[1][j], 0, 0, 0);
        }
        __syncthreads();
    }

    #pragma unroll
    for (int i = 0; i < 2; i++)
        #pragma unroll
        for (int j = 0; j < 2; j++) {
            int rb = w0 + wr + i * 16 + quad * 4;
            int cc = n0 + wc + j * 16 + l15;
            #pragma unroll
            for (int rr = 0; rr < 4; rr++)
                M[dstb + (size_t)(rb + rr) * NN + cc] = f2h(acc[i][j][rr]);
        }
}

// ---------------- plain -> fragment-major: chunk t = (T*128 + kc)*64 + rowloc ----------------
__global__ void k_m2frag(const unsigned short* __restrict__ P, unsigned short* __restrict__ F) {
    size_t t = (size_t)blockIdx.x * 256 + threadIdx.x;
    int rowloc = (int)(t & 63);
    int kc = (int)((t >> 6) & 127);
    int T = (int)(t >> 13);
    size_t src = ((size_t)(T * 64 + rowloc) * NN) + kc * 8;
    *(uint4*)(F + t * 8) = *(const uint4*)(P + src);
}

// ---------------- W -> fragment-major fp16 hi/lo: chunk (hl,cj,ks), lane-ordered ----------------
__global__ void k_wfrag(const float* __restrict__ W, unsigned short* __restrict__ Wf, int KS) {
    int idx = blockIdx.x * 256 + threadIdx.x;
    int e = idx & 7, l = (idx >> 3) & 63;
    int rest = idx >> 9;
    int ks = rest % KS;
    int rest2 = rest / KS;
    int cj = rest2 & 3, hl = rest2 >> 2;
    int c = cj * 16 + (l & 15);
    int k = ks * 32 + (l >> 4) * 8 + e;
    float w = W[(size_t)k * HH + c];
    unsigned short hi = f2h(w);
    Wf[idx] = hl ? f2h(w - h2f(hi)) : hi;
}

// ---------------- encoder, ALL t in one dispatch -> XTall[t][b][c][n] fp16 ----------------
__global__ void k_encT(const float* __restrict__ x, const float* __restrict__ W_enc,
                       const float* __restrict__ b_enc, const float* __restrict__ emb,
                       unsigned short* __restrict__ XTall) {
    int gb = blockIdx.x;
    int t = gb >> 10;
    int b = (gb >> 6) & 15;
    int c = gb & 63;
    int n8 = threadIdx.x * 8;
    float w[FF];
    #pragma unroll
    for (int f = 0; f < FF; f++) w[f] = W_enc[f * HH + c];
    float be = b_enc[c];
    unsigned short h8[8];
    #pragma unroll
    for (int j = 0; j < 8; j++) {
        int n = n8 + j;
        const float* xr = x + (((size_t)b * TT + t) * NN + n) * FF;
        float acc = be + emb[(size_t)n * HH + c];
        #pragma unroll
        for (int f = 0; f < FF; f++) acc += xr[f] * w[f];
        h8[j] = f2h(acc);
    }
    size_t o = ((size_t)(t * BB + b) * 64 + c) * NN + n8;
    *(uint4*)(XTall + o) = *(uint4*)h8;
}

// ---------------- async-LDS stacked hop, single fp16, BK=64, fp16 output ----------------
// M fragment-major; X operand from Xx [b][64][n] (x-cols) or Xh [b][64][n] (h-cols).
__global__ __launch_bounds__(256) void k_hopA(
        const unsigned short* __restrict__ Mf,
        const unsigned short* __restrict__ Xx,
        const unsigned short* __restrict__ Xh,
        int in_off,
        unsigned short* __restrict__ Yout, int out_stride, int out_gmul, int out_off) {
    int rt = blockIdx.x;
    int g = rt >> 3;
    int n0 = (rt & 7) * 128;
    int b = blockIdx.z;
    int c0 = in_off + blockIdx.y * 64;

    __shared__ unsigned short sA[16 * 512];   // 128 rows x 64 K
    __shared__ unsigned short sX[8 * 512];    // 64 cols x 64 K

    int tid = threadIdx.x;
    int lane = tid & 63, wave = tid >> 6;
    int half = wave >> 1;
    int ch_ = (wave & 1) * 32;
    int l15 = lane & 15, quad = lane >> 4;

    const unsigned short* Xb;
    int crow0;
    if (c0 >= 64) { Xb = Xh + (size_t)b * 64 * NN; crow0 = c0 - 64; }
    else          { Xb = Xx + (size_t)b * 64 * NN; crow0 = c0; }

    v4f acc[4][2];
    #pragma unroll
    for (int i = 0; i < 4; i++)
        #pragma unroll
        for (int j = 0; j < 2; j++) { acc[i][j][0]=0.f; acc[i][j][1]=0.f; acc[i][j][2]=0.f; acc[i][j][3]=0.f; }

    for (int k0 = 0; k0 < NN; k0 += 64) {
        #pragma unroll
        for (int s = 0; s < 6; s++) {
            int id = wave + s * 4;
            if (id < 16) {
                int ah = id >> 3, kh = (id >> 2) & 1, rf = id & 3;
                const unsigned short* src = Mf +
                    ((size_t)(rt * 2 + ah) * 8192 +
                     (size_t)((k0 >> 3) + kh * 4 + quad) * 64 + rf * 16 + l15) * 8;
                gl_lds16(src, &sA[id * 512]);
            } else {
                int xi = id - 16, cj = xi >> 1, kh = xi & 1;
                const unsigned short* src = Xb +
                    (size_t)(crow0 + cj * 16 + l15) * NN + k0 + kh * 32 + quad * 8;
                gl_lds16(src, &sX[xi * 512]);
            }
        }
        __syncthreads();   // drains vmcnt -> staged data visible

        int lu = lane * 8;
        #pragma unroll
        for (int kh = 0; kh < 2; kh++) {
            v8h a[4], bx[2];
            #pragma unroll
            for (int rf = 0; rf < 4; rf++)
                a[rf] = *(const v8h*)&sA[(half * 8 + kh * 4 + rf) * 512 + lu];
            #pragma unroll
            for (int j = 0; j < 2; j++) {
                int cj = (wave & 1) * 2 + j;
                bx[j] = *(const v8h*)&sX[(cj * 2 + kh) * 512 + lu];
            }
            #pragma unroll
            for (int rf = 0; rf < 4; rf++)
                #pragma unroll
                for (int j = 0; j < 2; j++)
                    acc[rf][j] = __builtin_amdgcn_mfma_f32_16x16x32_f16(a[rf], bx[j], acc[rf][j], 0, 0, 0);
        }
        __syncthreads();
    }

    unsigned short* Y = Yout + (size_t)b * NN * out_stride + out_gmul * g + out_off + blockIdx.y * 64 + ch_;
    #pragma unroll
    for (int rf = 0; rf < 4; rf++)
        #pragma unroll
        for (int j = 0; j < 2; j++) {
            int rbase = n0 + half * 64 + rf * 16 + quad * 4;
            int cc = j * 16 + l15;
            #pragma unroll
            for (int rr = 0; rr < 4; rr++)
                Y[(size_t)(rbase + rr) * out_stride + cc] = f2h(acc[rf][j][rr]);
        }
}

// ---------------- gates via MFMA: waves = gate x row-half; K=512 fp16, W hi+lo split ----------------
__global__ __launch_bounds__(256) void k_gatesM(
        const unsigned short* __restrict__ feats,
        const unsigned short* __restrict__ Wf_r, const unsigned short* __restrict__ Wf_u,
        const float* __restrict__ b_r, const float* __restrict__ b_u,
        const float* __restrict__ h,
        unsigned short* __restrict__ Xh, float* __restrict__ ubuf) {
    int row0 = blockIdx.x * 64;
    int b = row0 >> 10, n0g = row0 & 1023;
    int tid = threadIdx.x, lane = tid & 63, wave = tid >> 6;
    int gate = wave >> 1;              // 0 = r, 1 = u
    int rhalf = (wave & 1) * 32;
    int l15 = lane & 15, quad = lane >> 4;
    const unsigned short* Wf = gate ? Wf_u : Wf_r;
    const float* bias = gate ? b_u : b_r;

    __shared__ unsigned short sT[64 * 72];   // [c][n] pitch 72

    v4f acc[2][4];
    #pragma unroll
    for (int rf = 0; rf < 2; rf++)
        #pragma unroll
        for (int cj = 0; cj < 4; cj++) { acc[rf][cj][0]=0.f; acc[rf][cj][1]=0.f; acc[rf][cj][2]=0.f; acc[rf][cj][3]=0.f; }

    const unsigned short* fbase = feats + (size_t)(row0 + rhalf + l15) * FS + quad * 8;
    #pragma unroll 2
    for (int ks = 0; ks < 16; ks++) {
        v8h a0 = *(const v8h*)(fbase + ks * 32);
        v8h a1 = *(const v8h*)(fbase + 16 * FS + ks * 32);
        #pragma unroll
        for (int hl = 0; hl < 2; hl++)
            #pragma unroll
            for (int cj = 0; cj < 4; cj++) {
                v8h bf = *(const v8h*)(Wf + (size_t)((hl * 4 + cj) * 16 + ks) * 512 + lane * 8);
                acc[0][cj] = __builtin_amdgcn_mfma_f32_16x16x32_f16(a0, bf, acc[0][cj], 0, 0, 0);
                acc[1][cj] = __builtin_amdgcn_mfma_f32_16x16x32_f16(a1, bf, acc[1][cj], 0, 0, 0);
            }
    }

    if (gate == 0) {
        #pragma unroll
        for (int rf = 0; rf < 2; rf++)
            #pragma unroll
            for (int cj = 0; cj < 4; cj++) {
                int c = cj * 16 + l15;
                float bb = bias[c];
                #pragma unroll
                for (int rr = 0; rr < 4; rr++) {
                    int nloc = rhalf + rf * 16 + quad * 4 + rr;
                    float r = 1.f / (1.f + expf(-(acc[rf][cj][rr] + bb)));
                    float rh = r * h[(size_t)(row0 + nloc) * HH + c];
                    sT[c * 72 + nloc] = f2h(rh);
                }
            }
    } else {
        #pragma unroll
        for (int rf = 0; rf < 2; rf++)
            #pragma unroll
            for (int cj = 0; cj < 4; cj++) {
                int c = cj * 16 + l15;
                float bb = bias[c];
                #pragma unroll
                for (int rr = 0; rr < 4; rr++) {
                    int nloc = rhalf + rf * 16 + quad * 4 + rr;
                    float u = 1.f / (1.f + expf(-(acc[rf][cj][rr] + bb)));
                    ubuf[(size_t)(row0 + nloc) * HH + c] = u;   // u stays exact f32
                }
            }
    }
    __syncthreads();
    #pragma unroll
    for (int i = 0; i < 2; i++) {
        int ii = tid * 2 + i;
        int c = ii >> 3, n8 = (ii & 7) * 8;
        *(uint4*)(Xh + ((size_t)b * 64 + c) * NN + n0g + n8) = *(uint4*)&sT[c * 72 + n8];
    }
}

// ---------------- candidate via MFMA + h update; new h -> h f32 AND Xh fp16 ----------------
__global__ __launch_bounds__(256) void k_candM(
        const unsigned short* __restrict__ feats,
        const unsigned short* __restrict__ Wf_c, const float* __restrict__ b_c,
        const float* __restrict__ ubuf,
        float* __restrict__ h, unsigned short* __restrict__ Xh) {
    int row0 = blockIdx.x * 64;
    int b = row0 >> 10, n0g = row0 & 1023;
    int tid = threadIdx.x, lane = tid & 63, wave = tid >> 6;
    int l15 = lane & 15, quad = lane >> 4;

    __shared__ unsigned short sT[64 * 72];

    v4f acc[4];
    #pragma unroll
    for (int cj = 0; cj < 4; cj++) { acc[cj][0]=0.f; acc[cj][1]=0.f; acc[cj][2]=0.f; acc[cj][3]=0.f; }

    const unsigned short* fbase = feats + (size_t)(row0 + wave * 16 + l15) * FS + quad * 8;
    #pragma unroll 2
    for (int ks = 0; ks < 16; ks++) {
        v8h a = *(const v8h*)(fbase + ks * 32);
        #pragma unroll
        for (int hl = 0; hl < 2; hl++)
            #pragma unroll
            for (int cj = 0; cj < 4; cj++) {
                v8h bf = *(const v8h*)(Wf_c + (size_t)((hl * 4 + cj) * 16 + ks) * 512 + lane * 8);
                acc[cj] = __builtin_amdgcn_mfma_f32_16x16x32_f16(a, bf, acc[cj], 0, 0, 0);
            }
    }

    #pragma unroll
    for (int cj = 0; cj < 4; cj++) {
        int c = cj * 16 + l15;
        float bb = b_c[c];
        #pragma unroll
        for (int rr = 0; rr < 4; rr++) {
            int nloc = wave * 16 + quad * 4 + rr;
            size_t o = (size_t)(row0 + nloc) * HH + c;
            float cv = tanhf(acc[cj][rr] + bb);
            float u = ubuf[o];
            float hv = h[o];
            float hn = u * hv + (1.f - u) * cv;
            h[o] = hn;
            sT[c * 72 + nloc] = f2h(hn);
        }
    }
    __syncthreads();
    #pragma unroll
    for (int i = 0; i < 2; i++) {
        int ii = tid * 2 + i;
        int c = ii >> 3, n8 = (ii & 7) * 8;
        *(uint4*)(Xh + ((size_t)b * 64 + c) * NN + n0g + n8) = *(uint4*)&sT[c * 72 + n8];
    }
}

// ---------------- z = featd @ W_diff + b_diff via MFMA (K=320) ----------------
__global__ __launch_bounds__(256) void k_zM(
        const unsigned short* __restrict__ featd,
        const unsigned short* __restrict__ Wf_z, const float* __restrict__ b_diff,
        float* __restrict__ z) {
    int row0 = blockIdx.x * 64;
    int tid = threadIdx.x, lane = tid & 63, wave = tid >> 6;
    int l15 = lane & 15, quad = lane >> 4;

    v4f acc[4];
    #pragma unroll
    for (int cj = 0; cj < 4; cj++) { acc[cj][0]=0.f; acc[cj][1]=0.f; acc[cj][2]=0.f; acc[cj][3]=0.f; }

    const unsigned short* fbase = featd + (size_t)(row0 + wave * 16 + l15) * DIN + quad * 8;
    #pragma unroll 2
    for (int ks = 0; ks < 10; ks++) {
        v8h a = *(const v8h*)(fbase + ks * 32);
        #pragma unroll
        for (int hl = 0; hl < 2; hl++)
            #pragma unroll
            for (int cj = 0; cj < 4; cj++) {
                v8h bf = *(const v8h*)(Wf_z + (size_t)((hl * 4 + cj) * 10 + ks) * 512 + lane * 8);
                acc[cj] = __builtin_amdgcn_mfma_f32_16x16x32_f16(a, bf, acc[cj], 0, 0, 0);
            }
    }
    #pragma unroll
    for (int cj = 0; cj < 4; cj++) {
        int c = cj * 16 + l15;
        float bb = b_diff[c];
        #pragma unroll
        for (int rr = 0; rr < 4; rr++)
            z[(size_t)(row0 + wave * 16 + quad * 4 + rr) * HH + c] = acc[cj][rr] + bb;
    }
}

// ---------------- DiffConv operator build ----------------
__global__ void k_deg(const int* __restrict__ ei32, const float* __restrict__ ew,
                      float* __restrict__ degd, float* __restrict__ degs) {
    int e = blockIdx.x * 256 + threadIdx.x;
    float w = ew[e];
    atomicAdd(&degd[ei32[EE + e]], w);
    atomicAdd(&degs[ei32[e]], w);
}
__global__ void k_spadd(const int* __restrict__ ei32, const float* __restrict__ ew,
                        const float* __restrict__ degd, const float* __restrict__ degs,
                        float* __restrict__ temp) {
    int e = blockIdx.x * 256 + threadIdx.x;
    int s = ei32[e], d = ei32[EE + e];
    float w = ew[e];
    float dd = degd[d], ds = degs[s];
    float wfv = dd > 0.f ? w / dd : 0.f;
    float wbv = ds > 0.f ? w / ds : 0.f;
    atomicAdd(&temp[(size_t)d * NN + s], wfv);
    atomicAdd(&temp[(size_t)NN * NN + (size_t)s * NN + d], wbv);
}
__global__ void k_spconv(const float* __restrict__ temp, unsigned short* __restrict__ Mp) {
    size_t i0 = ((size_t)blockIdx.x * 256 + threadIdx.x) * 8;
    size_t dst = (i0 < (size_t)NN * NN) ? i0 : i0 + (size_t)NN * NN;
    unsigned short h8[8];
    #pragma unroll
    for (int j = 0; j < 8; j++) h8[j] = f2h(temp[i0 + j]);
    *(uint4*)(Mp + dst) = *(uint4*)h8;
}

__global__ void k_featd_h(const float* __restrict__ h, unsigned short* __restrict__ featd) {
    size_t idx = (size_t)blockIdx.x * 256 + threadIdx.x;
    size_t row = idx >> 6; int c = (int)(idx & 63);
    featd[row * DIN + c] = f2h(h[idx]);
}

__global__ void k_dec(const float* __restrict__ z, const float* __restrict__ W_dec,
                      const float* __restrict__ b_dec, float* __restrict__ out) {
    size_t idx = (size_t)blockIdx.x * 256 + threadIdx.x;
    size_t row = idx / ODIM; int o = (int)(idx % ODIM);
    const float* zr = z + row * HH;
    float acc = b_dec[o];
    for (int k = 0; k < HH; k++) acc += zr[k] * W_dec[k * ODIM + o];
    int b = (int)(row >> 10), n = (int)(row & 1023);
    int t = o >> 3, f = o & 7;
    out[(((size_t)b * TT + t) * NN + n) * FF + f] = acc;
}

extern "C" void kernel_launch(void* const* d_in, const int* in_sizes, int n_in,
                              void* d_out, int out_size, void* d_ws, size_t ws_size,
                              hipStream_t stream) {
    const float* x      = (const float*)d_in[0];
    const int*   eiraw  = (const int*)  d_in[1];
    const float* ew     = (const float*)d_in[2];
    const float* adj    = (const float*)d_in[3];
    const float* W_enc  = (const float*)d_in[4];
    const float* b_enc  = (const float*)d_in[5];
    const float* emb    = (const float*)d_in[6];
    const float* W_r    = (const float*)d_in[7];
    const float* b_r    = (const float*)d_in[8];
    const float* W_u    = (const float*)d_in[9];
    const float* b_u    = (const float*)d_in[10];
    const float* W_c    = (const float*)d_in[11];
    const float* b_c    = (const float*)d_in[12];
    const float* W_diff = (const float*)d_in[13];
    const float* b_diff = (const float*)d_in[14];
    const float* W_dec  = (const float*)d_in[15];
    const float* b_dec  = (const float*)d_in[16];

    // ---- workspace ~58.8 MiB ----
    unsigned short* Mf    = (unsigned short*)d_ws;                       // 8 MiB
    unsigned short* Xh    = Mf + (size_t)4096 * NN;                      // 2 MiB [b][64][n]
    unsigned short* feats = Xh + (size_t)BB * 64 * NN;                   // 16 MiB fp16 [16384][512]
    unsigned short* featd = feats;                                       // overlay 10 MiB [16384][320]
    float* h    = (float*)(feats + (size_t)BB * NN * FS);                // 4 MiB
    float* z    = h;                                                     // overlay
    float* ubuf = h + (size_t)BB * NN * HH;                              // 4 MiB
    unsigned short* XTall = (unsigned short*)(ubuf + (size_t)BB * NN * HH); // 24 MiB [t][b][64][n]
    unsigned short* Mp    = XTall;                                       // 8 MiB overlay
    float* sptmp = (float*)(XTall + (size_t)4096 * NN);                  // 8 MiB overlay
    unsigned short* Wf_r = XTall + (size_t)TT * BB * 64 * NN;            // 128 KiB
    unsigned short* Wf_u = Wf_r + 65536;
    unsigned short* Wf_c = Wf_u + 65536;
    unsigned short* Wf_z = Wf_c + 65536;                                 // 80 KiB
    float* rinv = (float*)(Wf_z + 40960);
    float* cinv = rinv + NN;
    int*   eifl = (int*)(cinv + NN);
    int*   ei32 = eifl + 4;
    float* degd = (float*)(ei32 + 2 * EE);
    float* degs = degd + NN;

    hipMemsetAsync(h, 0, (size_t)BB * NN * HH * 4, stream);
    hipMemsetAsync(Xh, 0, (size_t)BB * 64 * NN * 2, stream);   // h-cols = 0 at t=0

    // ---- build plain M = [Af; Af^2; Ab; Ab^2] (fp16), convert to fragment-major ----
    k_rowsum<<<NN, 256, 0, stream>>>(adj, rinv);
    k_colsum<<<NN / 256, 256, 0, stream>>>(adj, cinv);
    k_prepA<<<dim3(16, 16), 256, 0, stream>>>(adj, rinv, cinv, Mp);
    k_msq<<<dim3(16, 16, 2), 256, 0, stream>>>(Mp);
    k_m2frag<<<2048, 256, 0, stream>>>(Mp, Mf);

    // ---- weight fragments (hi/lo split fp16) ----
    k_wfrag<<<(2 * 4 * 16 * 512) / 256, 256, 0, stream>>>(W_r, Wf_r, 16);
    k_wfrag<<<(2 * 4 * 16 * 512) / 256, 256, 0, stream>>>(W_u, Wf_u, 16);
    k_wfrag<<<(2 * 4 * 16 * 512) / 256, 256, 0, stream>>>(W_c, Wf_c, 16);
    k_wfrag<<<(2 * 4 * 10 * 512) / 256, 256, 0, stream>>>(W_diff, Wf_z, 10);

    // ---- encoder for ALL t (overwrites Mp/sptmp region -> after m2frag) ----
    k_encT<<<TT * BB * 64, 128, 0, stream>>>(x, W_enc, b_enc, emb, XTall);

    for (int t = 0; t < TT; t++) {
        const unsigned short* Xx_t = XTall + (size_t)t * BB * 64 * NN;
        // 4 operators x [x|h] -> feats cols g*128 + 0..127 (fp16)
        k_hopA<<<dim3(32, 2, 16), 256, 0, stream>>>(Mf, Xx_t, Xh, 0, feats, FS, 128, 0);
        // gates: rh -> Xh (fp16), u -> ubuf (f32)
        k_gatesM<<<BB * NN / 64, 256, 0, stream>>>(feats, Wf_r, Wf_u, b_r, b_u, h, Xh, ubuf);
        // 4 operators @ rh -> feats h-cols
        k_hopA<<<dim3(32, 1, 16), 256, 0, stream>>>(Mf, Xx_t, Xh, 64, feats, FS, 128, 64);
        // candidate + h update
        k_candM<<<BB * NN / 64, 256, 0, stream>>>(feats, Wf_c, b_c, ubuf, h, Xh);
    }

    // ---- DiffConv readout ----
    k_ei_detect<<<1, 256, 0, stream>>>(eiraw, eifl);
    k_ei_norm<<<2 * EE / 256, 256, 0, stream>>>(eiraw, eifl, ei32);
    hipMemsetAsync(degd, 0, (size_t)2 * NN * 4, stream);
    hipMemsetAsync(sptmp, 0, (size_t)2 * NN * NN * 4, stream);
    k_deg<<<EE / 256, 256, 0, stream>>>(ei32, ew, degd, degs);
    k_spadd<<<EE / 256, 256, 0, stream>>>(ei32, ew, degd, degs, sptmp);
    k_spconv<<<2 * NN * NN / (256 * 8), 256, 0, stream>>>(sptmp, Mp);
    k_msq<<<dim3(16, 16, 2), 256, 0, stream>>>(Mp);
    k_m2frag<<<2048, 256, 0, stream>>>(Mp, Mf);
    k_featd_h<<<BB * NN * HH / 256, 256, 0, stream>>>(h, featd);
    // [Sf;Sf2;Sb;Sb2] @ h (fp16 in Xh) -> featd cols 64 + g*64
    k_hopA<<<dim3(32, 1, 16), 256, 0, stream>>>(Mf, XTall, Xh, 64, featd, DIN, 64, 64);
    k_zM<<<BB * NN / 64, 256, 0, stream>>>(featd, Wf_z, b_diff, z);
    k_dec<<<(BB * NN * ODIM) / 256, 256, 0, stream>>>(z, W_dec, b_dec, (float*)d_out);
}

// Round 3
// 1062.627 us; speedup vs baseline: 2.2543x; 1.2298x over previous
//
#include <hip/hip_runtime.h>
#include <math.h>

#define BB 16
#define TT 12
#define NN 1024
#define FF 8
#define HH 64
#define EE 32768
#define DIN 320   // H * (2K+1)
#define ODIM 96   // F * HORIZON
#define APAD 40   // k_msq LDS row stride

typedef _Float16 v8h __attribute__((ext_vector_type(8)));
typedef float v4f __attribute__((ext_vector_type(4)));

__device__ __forceinline__ unsigned short f2h(float v) {
    _Float16 h = (_Float16)v;          // RNE v_cvt_f16_f32
    unsigned short u;
    __builtin_memcpy(&u, &h, 2);
    return u;
}
__device__ __forceinline__ float h2f(unsigned short u) {
    _Float16 h;
    __builtin_memcpy(&h, &u, 2);
    return (float)h;
}
// async global->LDS, 16B per lane; LDS dst = wave-uniform base + lane*16
__device__ __forceinline__ void gl_lds16(const void* g, void* l) {
    __builtin_amdgcn_global_load_lds(
        (const __attribute__((address_space(1))) unsigned int*)g,
        (__attribute__((address_space(3))) unsigned int*)l, 16, 0, 0);
}

// ---------------- edge_index insurance ----------------
__global__ void k_ei_detect(const int* __restrict__ ei_raw, int* __restrict__ flag) {
    __shared__ int s[256];
    s[threadIdx.x] = ei_raw[2 * threadIdx.x + 1];
    __syncthreads();
    for (int st = 128; st > 0; st >>= 1) {
        if (threadIdx.x < st) s[threadIdx.x] |= s[threadIdx.x + st];
        __syncthreads();
    }
    if (threadIdx.x == 0) flag[0] = (s[0] == 0) ? 1 : 0;
}
__global__ void k_ei_norm(const int* __restrict__ ei_raw, const int* __restrict__ flag,
                          int* __restrict__ ei32) {
    int j = blockIdx.x * 256 + threadIdx.x;
    ei32[j] = flag[0] ? ei_raw[2 * j] : ei_raw[j];
}

// ---------------- support normalization ----------------
__global__ void k_rowsum(const float* __restrict__ adj, float* __restrict__ rinv) {
    __shared__ float s[256];
    int i = blockIdx.x;
    float acc = 0.f;
    for (int j = threadIdx.x; j < NN; j += 256) acc += adj[i * NN + j];
    s[threadIdx.x] = acc;
    __syncthreads();
    for (int st = 128; st > 0; st >>= 1) {
        if (threadIdx.x < st) s[threadIdx.x] += s[threadIdx.x + st];
        __syncthreads();
    }
    if (threadIdx.x == 0) rinv[i] = (s[0] != 0.f) ? 1.f / s[0] : 0.f;
}
__global__ void k_colsum(const float* __restrict__ adj, float* __restrict__ cinv) {
    int j = blockIdx.x * 256 + threadIdx.x;
    float acc = 0.f;
    for (int i = 0; i < NN; i++) acc += adj[i * NN + j];
    cinv[j] = (acc != 0.f) ? 1.f / acc : 0.f;
}

// ---------------- Af -> plain rows 0..1023, Ab -> plain rows 2048..3071 (single fp16) ----------------
__global__ __launch_bounds__(256) void k_prepA(
        const float* __restrict__ adj, const float* __restrict__ rinv,
        const float* __restrict__ cinv, unsigned short* __restrict__ Mp) {
    int w0 = blockIdx.x * 64, v0 = blockIdx.y * 64;
    __shared__ float T[64][68];
    int row = threadIdx.x >> 2, cs = (threadIdx.x & 3) * 16;
    #pragma unroll
    for (int j = 0; j < 4; j++)
        *(float4*)&T[row][cs + j * 4] = *(const float4*)(adj + (size_t)(w0 + row) * NN + v0 + cs + j * 4);
    __syncthreads();
    {
        float sc = rinv[w0 + row];
        unsigned short h8[16];
        #pragma unroll
        for (int j = 0; j < 16; j++) h8[j] = f2h(T[row][cs + j] * sc);
        size_t ofs = (size_t)(w0 + row) * NN + v0 + cs;
        ((uint4*)(Mp + ofs))[0] = *(uint4*)&h8[0];
        ((uint4*)(Mp + ofs))[1] = *(uint4*)&h8[8];
    }
    {
        float sc = cinv[v0 + row];
        unsigned short h8[16];
        #pragma unroll
        for (int j = 0; j < 16; j++) h8[j] = f2h(T[cs + j][row] * sc);
        size_t ofs = (size_t)2048 * NN + (size_t)(v0 + row) * NN + w0 + cs;
        ((uint4*)(Mp + ofs))[0] = *(uint4*)&h8[0];
        ((uint4*)(Mp + ofs))[1] = *(uint4*)&h8[8];
    }
}

// ---------------- plain M rows (zz) squared: rows zz*2048 -> zz*2048+1024 ----------------
__global__ __launch_bounds__(256) void k_msq(unsigned short* __restrict__ M) {
    int zz = blockIdx.z;
    size_t srcb = (size_t)zz * 2048 * NN;
    size_t dstb = srcb + (size_t)1024 * NN;
    int w0 = blockIdx.x * 64, n0 = blockIdx.y * 64;

    __shared__ unsigned short sA[64 * APAD];
    __shared__ unsigned short sB[64 * APAD];

    int tid = threadIdx.x;
    int lane = tid & 63, wave = tid >> 6;
    int wr = (wave >> 1) * 32, wc = (wave & 1) * 32;
    int l15 = lane & 15, quad = lane >> 4;
    int arow = tid >> 2, akk = (tid & 3) * 8;
    int bkr = tid & 31, bc8 = (tid >> 5) * 8;

    v4f acc[2][2];
    #pragma unroll
    for (int i = 0; i < 2; i++)
        #pragma unroll
        for (int j = 0; j < 2; j++) { acc[i][j][0]=0.f; acc[i][j][1]=0.f; acc[i][j][2]=0.f; acc[i][j][3]=0.f; }

    for (int k0 = 0; k0 < NN; k0 += 32) {
        *(uint4*)&sA[arow * APAD + akk] = *(const uint4*)(M + srcb + (size_t)(w0 + arow) * NN + k0 + akk);
        uint4 bh = *(const uint4*)(M + srcb + (size_t)(k0 + bkr) * NN + n0 + bc8);
        const unsigned short* ph = (const unsigned short*)&bh;
        #pragma unroll
        for (int j = 0; j < 8; j++) sB[(bc8 + j) * APAD + bkr] = ph[j];
        __syncthreads();

        v8h a0 = *(const v8h*)&sA[(wr + l15) * APAD + quad * 8];
        v8h a1 = *(const v8h*)&sA[(wr + 16 + l15) * APAD + quad * 8];
        #pragma unroll
        for (int j = 0; j < 2; j++) {
            v8h bb = *(const v8h*)&sB[(wc + j * 16 + l15) * APAD + quad * 8];
            acc[0][j] = __builtin_amdgcn_mfma_f32_16x16x32_f16(a0, bb, acc[0][j], 0, 0, 0);
            acc[1][j] = __builtin_amdgcn_mfma_f32_16x16x32_f16(a1, bb, acc[1][j], 0, 0, 0);
        }
        __syncthreads();
    }

    #pragma unroll
    for (int i = 0; i < 2; i++)
        #pragma unroll
        for (int j = 0; j < 2; j++) {
            int rb = w0 + wr + i * 16 + quad * 4;
            int cc = n0 + wc + j * 16 + l15;
            #pragma unroll
            for (int rr = 0; rr < 4; rr++)
                M[dstb + (size_t)(rb + rr) * NN + cc] = f2h(acc[i][j][rr]);
        }
}

// ---------------- plain -> fragment-major: chunk t = (T*128 + kc)*64 + rowloc ----------------
__global__ void k_m2frag(const unsigned short* __restrict__ P, unsigned short* __restrict__ F) {
    size_t t = (size_t)blockIdx.x * 256 + threadIdx.x;
    int rowloc = (int)(t & 63);
    int kc = (int)((t >> 6) & 127);
    int T = (int)(t >> 13);
    size_t src = ((size_t)(T * 64 + rowloc) * NN) + kc * 8;
    *(uint4*)(F + t * 8) = *(const uint4*)(P + src);
}

// ---------------- x -> XallT rows: XallT[(t*16+b)*8+f][n] fp16 ----------------
__global__ void k_xT(const float* __restrict__ x, unsigned short* __restrict__ XallT) {
    int bx = blockIdx.x;            // t*16+b
    int t = bx >> 4, b = bx & 15;
    int tid = threadIdx.x;
    int f = tid & 7, half = tid >> 3;   // half 0..31
    const float* xs = x + ((size_t)b * TT + t) * NN * FF + f;
    int n0 = half * 32;
    unsigned short v[32];
    #pragma unroll
    for (int i = 0; i < 32; i++) v[i] = f2h(xs[(size_t)(n0 + i) * FF]);
    unsigned short* dst = XallT + ((size_t)bx * 8 + f) * NN + n0;
    #pragma unroll
    for (int i = 0; i < 4; i++) *(uint4*)(dst + i * 8) = *(uint4*)&v[i * 8];
}
// ---------------- emb -> XallT rows 1536..1599: embT[c][n] ----------------
__global__ void k_embT(const float* __restrict__ emb, unsigned short* __restrict__ XallT) {
    int c = blockIdx.x;
    int n0 = threadIdx.x * 4;
    unsigned short v[4];
    #pragma unroll
    for (int j = 0; j < 4; j++) v[j] = f2h(emb[(size_t)(n0 + j) * HH + c]);
    *(uint2*)(XallT + (size_t)(1536 + c) * NN + n0) = *(uint2*)v;
}

// ---------------- batched x-hop: AX[tb][n][g*8+f] = (A_g^k x_tb), Eg[g][n][c] = A_g^k emb --------
__global__ __launch_bounds__(256) void k_hopX(
        const unsigned short* __restrict__ Mf,
        const unsigned short* __restrict__ XallT,
        unsigned short* __restrict__ AX, unsigned short* __restrict__ Eg) {
    int rt = blockIdx.x;
    int g = rt >> 3;
    int n0 = (rt & 7) * 128;
    int c0 = blockIdx.y * 64;

    __shared__ unsigned short sA[16 * 512];
    __shared__ unsigned short sX[8 * 512];

    int tid = threadIdx.x;
    int lane = tid & 63, wave = tid >> 6;
    int half = wave >> 1;
    int ch_ = (wave & 1) * 32;
    int l15 = lane & 15, quad = lane >> 4;

    v4f acc[4][2];
    #pragma unroll
    for (int i = 0; i < 4; i++)
        #pragma unroll
        for (int j = 0; j < 2; j++) { acc[i][j][0]=0.f; acc[i][j][1]=0.f; acc[i][j][2]=0.f; acc[i][j][3]=0.f; }

    for (int k0 = 0; k0 < NN; k0 += 64) {
        #pragma unroll
        for (int s = 0; s < 6; s++) {
            int id = wave + s * 4;
            if (id < 16) {
                int ah = id >> 3, kh = (id >> 2) & 1, rf = id & 3;
                const unsigned short* src = Mf +
                    ((size_t)(rt * 2 + ah) * 8192 +
                     (size_t)((k0 >> 3) + kh * 4 + quad) * 64 + rf * 16 + l15) * 8;
                gl_lds16(src, &sA[id * 512]);
            } else {
                int xi = id - 16, cj = xi >> 1, kh = xi & 1;
                const unsigned short* src = XallT +
                    (size_t)(c0 + cj * 16 + l15) * NN + k0 + kh * 32 + quad * 8;
                gl_lds16(src, &sX[xi * 512]);
            }
        }
        __syncthreads();

        int lu = lane * 8;
        #pragma unroll
        for (int kh = 0; kh < 2; kh++) {
            v8h a[4], bx[2];
            #pragma unroll
            for (int rf = 0; rf < 4; rf++)
                a[rf] = *(const v8h*)&sA[(half * 8 + kh * 4 + rf) * 512 + lu];
            #pragma unroll
            for (int j = 0; j < 2; j++) {
                int cj = (wave & 1) * 2 + j;
                bx[j] = *(const v8h*)&sX[(cj * 2 + kh) * 512 + lu];
            }
            #pragma unroll
            for (int rf = 0; rf < 4; rf++)
                #pragma unroll
                for (int j = 0; j < 2; j++)
                    acc[rf][j] = __builtin_amdgcn_mfma_f32_16x16x32_f16(a[rf], bx[j], acc[rf][j], 0, 0, 0);
        }
        __syncthreads();
    }

    if (blockIdx.y < 24) {
        #pragma unroll
        for (int rf = 0; rf < 4; rf++)
            #pragma unroll
            for (int j = 0; j < 2; j++) {
                int col = c0 + ch_ + j * 16 + l15;
                int tb = col >> 3, f = col & 7;
                #pragma unroll
                for (int rr = 0; rr < 4; rr++) {
                    int nrow = n0 + half * 64 + rf * 16 + quad * 4 + rr;
                    AX[((size_t)tb * NN + nrow) * 32 + g * 8 + f] = f2h(acc[rf][j][rr]);
                }
            }
    } else {
        #pragma unroll
        for (int rf = 0; rf < 4; rf++)
            #pragma unroll
            for (int j = 0; j < 2; j++) {
                int cc = ch_ + j * 16 + l15;   // 0..63
                #pragma unroll
                for (int rr = 0; rr < 4; rr++) {
                    int nrow = n0 + half * 64 + rf * 16 + quad * 4 + rr;
                    Eg[((size_t)(g << 10) + nrow) * 64 + cc] = f2h(acc[rf][j][rr]);
                }
            }
    }
}

// ---------------- Veg[G][g*8+f][c] = W_enc @ W_G(x-block g) ----------------
__global__ void k_veg(const float* __restrict__ W_enc,
                      const float* __restrict__ W_r, const float* __restrict__ W_u,
                      const float* __restrict__ W_c, float* __restrict__ Veg) {
    int idx = blockIdx.x * 256 + threadIdx.x;    // 3*32*64
    int c = idx & 63;
    int gf = (idx >> 6) & 31;
    int G = idx >> 11;
    int g = gf >> 3, f = gf & 7;
    const float* W = (G == 0) ? W_r : ((G == 1) ? W_u : W_c);
    float acc = 0.f;
    for (int c2 = 0; c2 < 64; c2++)
        acc += W_enc[f * HH + c2] * W[(size_t)(g * 128 + c2) * HH + c];
    Veg[idx] = acc;
}

// ---------------- constE[G][n][c] = sum_g (Eg[g][n] + b_enc) @ W_G(x-block g) ----------------
__global__ void k_constE(const unsigned short* __restrict__ Eg, const float* __restrict__ b_enc,
                         const float* __restrict__ W_r, const float* __restrict__ W_u,
                         const float* __restrict__ W_c, float* __restrict__ constE) {
    int G = blockIdx.y;
    int n = blockIdx.x * 4 + (threadIdx.x >> 6);
    int c = threadIdx.x & 63;
    const float* W = (G == 0) ? W_r : ((G == 1) ? W_u : W_c);
    float acc = 0.f;
    for (int g = 0; g < 4; g++)
        for (int c2 = 0; c2 < 64; c2++)
            acc += (h2f(Eg[((size_t)(g << 10) + n) * 64 + c2]) + b_enc[c2]) *
                   W[(size_t)(g * 128 + c2) * HH + c];
    constE[((size_t)G << 16) + (size_t)n * 64 + c] = acc;
}

// ---------------- gate W -> fragment-major: k<32 from Veg, k>=32 from W h-block ----------------
__global__ void k_wfrag2(const float* __restrict__ W, const float* __restrict__ Veg,
                         unsigned short* __restrict__ Wf) {
    int idx = blockIdx.x * 256 + threadIdx.x;   // 4*9*512 = 18432
    int e = idx & 7, l = (idx >> 3) & 63;
    int rest = idx >> 9;
    int ks = rest % 9, cj = rest / 9;
    int c = cj * 16 + (l & 15);
    int k = ks * 32 + (l >> 4) * 8 + e;
    float w;
    if (k < 32) w = Veg[(size_t)k * 64 + c];
    else { int kk = k - 32; int g = kk >> 6, c2 = kk & 63; w = W[(size_t)(g * 128 + 64 + c2) * HH + c]; }
    Wf[idx] = f2h(w);
}
// ---------------- linear W -> fragment-major (for W_diff, KS=10) ----------------
__global__ void k_wfragL(const float* __restrict__ W, unsigned short* __restrict__ Wf) {
    int idx = blockIdx.x * 256 + threadIdx.x;   // 4*10*512 = 20480
    int e = idx & 7, l = (idx >> 3) & 63;
    int rest = idx >> 9;
    int ks = rest % 10, cj = rest / 10;
    int c = cj * 16 + (l & 15);
    int k = ks * 32 + (l >> 4) * 8 + e;
    Wf[idx] = f2h(W[(size_t)k * HH + c]);
}

// ---------------- async-LDS stacked hop (h-side): Mf ops @ Xb[b][64][n] -> Y fp16 ----------------
__global__ __launch_bounds__(256) void k_hopA(
        const unsigned short* __restrict__ Mf,
        const unsigned short* __restrict__ Xb,
        unsigned short* __restrict__ Yout, int out_stride, int out_gmul, int out_off) {
    int rt = blockIdx.x;
    int g = rt >> 3;
    int n0 = (rt & 7) * 128;
    int b = blockIdx.z;

    __shared__ unsigned short sA[16 * 512];
    __shared__ unsigned short sX[8 * 512];

    int tid = threadIdx.x;
    int lane = tid & 63, wave = tid >> 6;
    int half = wave >> 1;
    int ch_ = (wave & 1) * 32;
    int l15 = lane & 15, quad = lane >> 4;

    const unsigned short* Xbase = Xb + (size_t)b * 64 * NN;

    v4f acc[4][2];
    #pragma unroll
    for (int i = 0; i < 4; i++)
        #pragma unroll
        for (int j = 0; j < 2; j++) { acc[i][j][0]=0.f; acc[i][j][1]=0.f; acc[i][j][2]=0.f; acc[i][j][3]=0.f; }

    for (int k0 = 0; k0 < NN; k0 += 64) {
        #pragma unroll
        for (int s = 0; s < 6; s++) {
            int id = wave + s * 4;
            if (id < 16) {
                int ah = id >> 3, kh = (id >> 2) & 1, rf = id & 3;
                const unsigned short* src = Mf +
                    ((size_t)(rt * 2 + ah) * 8192 +
                     (size_t)((k0 >> 3) + kh * 4 + quad) * 64 + rf * 16 + l15) * 8;
                gl_lds16(src, &sA[id * 512]);
            } else {
                int xi = id - 16, cj = xi >> 1, kh = xi & 1;
                const unsigned short* src = Xbase +
                    (size_t)(cj * 16 + l15) * NN + k0 + kh * 32 + quad * 8;
                gl_lds16(src, &sX[xi * 512]);
            }
        }
        __syncthreads();

        int lu = lane * 8;
        #pragma unroll
        for (int kh = 0; kh < 2; kh++) {
            v8h a[4], bx[2];
            #pragma unroll
            for (int rf = 0; rf < 4; rf++)
                a[rf] = *(const v8h*)&sA[(half * 8 + kh * 4 + rf) * 512 + lu];
            #pragma unroll
            for (int j = 0; j < 2; j++) {
                int cj = (wave & 1) * 2 + j;
                bx[j] = *(const v8h*)&sX[(cj * 2 + kh) * 512 + lu];
            }
            #pragma unroll
            for (int rf = 0; rf < 4; rf++)
                #pragma unroll
                for (int j = 0; j < 2; j++)
                    acc[rf][j] = __builtin_amdgcn_mfma_f32_16x16x32_f16(a[rf], bx[j], acc[rf][j], 0, 0, 0);
        }
        __syncthreads();
    }

    unsigned short* Y = Yout + (size_t)b * NN * out_stride + out_gmul * g + out_off + ch_;
    #pragma unroll
    for (int rf = 0; rf < 4; rf++)
        #pragma unroll
        for (int j = 0; j < 2; j++) {
            int rbase = n0 + half * 64 + rf * 16 + quad * 4;
            int cc = j * 16 + l15;
            #pragma unroll
            for (int rr = 0; rr < 4; rr++)
                Y[(size_t)(rbase + rr) * out_stride + cc] = f2h(acc[rf][j][rr]);
        }
}

// ---------------- gates via MFMA: K=288 = [AX(32) | Fh(256)]; rh -> Xh, u -> ubuf ----------------
__global__ __launch_bounds__(256) void k_gatesM(
        const unsigned short* __restrict__ AXt,   // [16][1024][32] (this t)
        const unsigned short* __restrict__ Fh,    // [16384][256]
        const unsigned short* __restrict__ Wf_r, const unsigned short* __restrict__ Wf_u,
        const float* __restrict__ b_r, const float* __restrict__ b_u,
        const float* __restrict__ constE,         // [3][1024][64]
        const float* __restrict__ h,
        unsigned short* __restrict__ Xh, float* __restrict__ ubuf) {
    int row0 = blockIdx.x * 64;
    int b = row0 >> 10, n0g = row0 & 1023;
    int tid = threadIdx.x, lane = tid & 63, wave = tid >> 6;
    int gate = wave >> 1;              // 0 = r, 1 = u
    int rhalf = (wave & 1) * 32;
    int l15 = lane & 15, quad = lane >> 4;
    const unsigned short* Wf = gate ? Wf_u : Wf_r;
    const float* bias = gate ? b_u : b_r;
    const float* cE = constE + ((size_t)gate << 16);

    __shared__ unsigned short sT[64 * 72];

    v4f acc[2][4];
    #pragma unroll
    for (int rf = 0; rf < 2; rf++)
        #pragma unroll
        for (int cj = 0; cj < 4; cj++) { acc[rf][cj][0]=0.f; acc[rf][cj][1]=0.f; acc[rf][cj][2]=0.f; acc[rf][cj][3]=0.f; }

    const unsigned short* ax = AXt + ((size_t)b * NN + n0g + rhalf + l15) * 32 + quad * 8;
    const unsigned short* fh = Fh + (size_t)(row0 + rhalf + l15) * 256 + quad * 8;
    {
        v8h a0 = *(const v8h*)ax;
        v8h a1 = *(const v8h*)(ax + 16 * 32);
        #pragma unroll
        for (int cj = 0; cj < 4; cj++) {
            v8h bf = *(const v8h*)(Wf + (size_t)(cj * 9) * 512 + lane * 8);
            acc[0][cj] = __builtin_amdgcn_mfma_f32_16x16x32_f16(a0, bf, acc[0][cj], 0, 0, 0);
            acc[1][cj] = __builtin_amdgcn_mfma_f32_16x16x32_f16(a1, bf, acc[1][cj], 0, 0, 0);
        }
    }
    #pragma unroll
    for (int ks = 1; ks < 9; ks++) {
        v8h a0 = *(const v8h*)(fh + (ks - 1) * 32);
        v8h a1 = *(const v8h*)(fh + 16 * 256 + (ks - 1) * 32);
        #pragma unroll
        for (int cj = 0; cj < 4; cj++) {
            v8h bf = *(const v8h*)(Wf + (size_t)(cj * 9 + ks) * 512 + lane * 8);
            acc[0][cj] = __builtin_amdgcn_mfma_f32_16x16x32_f16(a0, bf, acc[0][cj], 0, 0, 0);
            acc[1][cj] = __builtin_amdgcn_mfma_f32_16x16x32_f16(a1, bf, acc[1][cj], 0, 0, 0);
        }
    }

    if (gate == 0) {
        #pragma unroll
        for (int rf = 0; rf < 2; rf++)
            #pragma unroll
            for (int cj = 0; cj < 4; cj++) {
                int c = cj * 16 + l15;
                float bb = bias[c];
                #pragma unroll
                for (int rr = 0; rr < 4; rr++) {
                    int nloc = rhalf + rf * 16 + quad * 4 + rr;
                    float pre = acc[rf][cj][rr] + bb + cE[(size_t)(n0g + nloc) * 64 + c];
                    float r = 1.f / (1.f + expf(-pre));
                    sT[c * 72 + nloc] = f2h(r * h[(size_t)(row0 + nloc) * HH + c]);
                }
            }
    } else {
        #pragma unroll
        for (int rf = 0; rf < 2; rf++)
            #pragma unroll
            for (int cj = 0; cj < 4; cj++) {
                int c = cj * 16 + l15;
                float bb = bias[c];
                #pragma unroll
                for (int rr = 0; rr < 4; rr++) {
                    int nloc = rhalf + rf * 16 + quad * 4 + rr;
                    float pre = acc[rf][cj][rr] + bb + cE[(size_t)(n0g + nloc) * 64 + c];
                    float u = 1.f / (1.f + expf(-pre));
                    ubuf[(size_t)(row0 + nloc) * HH + c] = u;
                }
            }
    }
    __syncthreads();
    #pragma unroll
    for (int i = 0; i < 2; i++) {
        int ii = tid * 2 + i;
        int c = ii >> 3, n8 = (ii & 7) * 8;
        *(uint4*)(Xh + ((size_t)b * 64 + c) * NN + n0g + n8) = *(uint4*)&sT[c * 72 + n8];
    }
}

// ---------------- candidate via MFMA (K=288) + h update; new h -> h f32 AND Xh fp16 --------------
__global__ __launch_bounds__(256) void k_candM(
        const unsigned short* __restrict__ AXt,
        const unsigned short* __restrict__ Fh,
        const unsigned short* __restrict__ Wf_c, const float* __restrict__ b_c,
        const float* __restrict__ constE,
        const float* __restrict__ ubuf,
        float* __restrict__ h, unsigned short* __restrict__ Xh) {
    int row0 = blockIdx.x * 64;
    int b = row0 >> 10, n0g = row0 & 1023;
    int tid = threadIdx.x, lane = tid & 63, wave = tid >> 6;
    int l15 = lane & 15, quad = lane >> 4;
    const float* cE = constE + ((size_t)2 << 16);

    __shared__ unsigned short sT[64 * 72];

    v4f acc[4];
    #pragma unroll
    for (int cj = 0; cj < 4; cj++) { acc[cj][0]=0.f; acc[cj][1]=0.f; acc[cj][2]=0.f; acc[cj][3]=0.f; }

    const unsigned short* ax = AXt + ((size_t)b * NN + n0g + wave * 16 + l15) * 32 + quad * 8;
    const unsigned short* fh = Fh + (size_t)(row0 + wave * 16 + l15) * 256 + quad * 8;
    {
        v8h a = *(const v8h*)ax;
        #pragma unroll
        for (int cj = 0; cj < 4; cj++) {
            v8h bf = *(const v8h*)(Wf_c + (size_t)(cj * 9) * 512 + lane * 8);
            acc[cj] = __builtin_amdgcn_mfma_f32_16x16x32_f16(a, bf, acc[cj], 0, 0, 0);
        }
    }
    #pragma unroll
    for (int ks = 1; ks < 9; ks++) {
        v8h a = *(const v8h*)(fh + (ks - 1) * 32);
        #pragma unroll
        for (int cj = 0; cj < 4; cj++) {
            v8h bf = *(const v8h*)(Wf_c + (size_t)(cj * 9 + ks) * 512 + lane * 8);
            acc[cj] = __builtin_amdgcn_mfma_f32_16x16x32_f16(a, bf, acc[cj], 0, 0, 0);
        }
    }

    #pragma unroll
    for (int cj = 0; cj < 4; cj++) {
        int c = cj * 16 + l15;
        float bb = b_c[c];
        #pragma unroll
        for (int rr = 0; rr < 4; rr++) {
            int nloc = wave * 16 + quad * 4 + rr;
            size_t o = (size_t)(row0 + nloc) * HH + c;
            float pre = acc[cj][rr] + bb + cE[(size_t)(n0g + nloc) * 64 + c];
            float cv = tanhf(pre);
            float u = ubuf[o];
            float hv = h[o];
            float hn = u * hv + (1.f - u) * cv;
            h[o] = hn;
            sT[c * 72 + nloc] = f2h(hn);
        }
    }
    __syncthreads();
    #pragma unroll
    for (int i = 0; i < 2; i++) {
        int ii = tid * 2 + i;
        int c = ii >> 3, n8 = (ii & 7) * 8;
        *(uint4*)(Xh + ((size_t)b * 64 + c) * NN + n0g + n8) = *(uint4*)&sT[c * 72 + n8];
    }
}

// ---------------- z = featd @ W_diff + b_diff via MFMA (K=320) ----------------
__global__ __launch_bounds__(256) void k_zM(
        const unsigned short* __restrict__ featd,
        const unsigned short* __restrict__ Wf_z, const float* __restrict__ b_diff,
        float* __restrict__ z) {
    int row0 = blockIdx.x * 64;
    int tid = threadIdx.x, lane = tid & 63, wave = tid >> 6;
    int l15 = lane & 15, quad = lane >> 4;

    v4f acc[4];
    #pragma unroll
    for (int cj = 0; cj < 4; cj++) { acc[cj][0]=0.f; acc[cj][1]=0.f; acc[cj][2]=0.f; acc[cj][3]=0.f; }

    const unsigned short* fbase = featd + (size_t)(row0 + wave * 16 + l15) * DIN + quad * 8;
    #pragma unroll 2
    for (int ks = 0; ks < 10; ks++) {
        v8h a = *(const v8h*)(fbase + ks * 32);
        #pragma unroll
        for (int cj = 0; cj < 4; cj++) {
            v8h bf = *(const v8h*)(Wf_z + (size_t)(cj * 10 + ks) * 512 + lane * 8);
            acc[cj] = __builtin_amdgcn_mfma_f32_16x16x32_f16(a, bf, acc[cj], 0, 0, 0);
        }
    }
    #pragma unroll
    for (int cj = 0; cj < 4; cj++) {
        int c = cj * 16 + l15;
        float bb = b_diff[c];
        #pragma unroll
        for (int rr = 0; rr < 4; rr++)
            z[(size_t)(row0 + wave * 16 + quad * 4 + rr) * HH + c] = acc[cj][rr] + bb;
    }
}

// ---------------- DiffConv operator build ----------------
__global__ void k_deg(const int* __restrict__ ei32, const float* __restrict__ ew,
                      float* __restrict__ degd, float* __restrict__ degs) {
    int e = blockIdx.x * 256 + threadIdx.x;
    float w = ew[e];
    atomicAdd(&degd[ei32[EE + e]], w);
    atomicAdd(&degs[ei32[e]], w);
}
__global__ void k_spadd(const int* __restrict__ ei32, const float* __restrict__ ew,
                        const float* __restrict__ degd, const float* __restrict__ degs,
                        float* __restrict__ temp) {
    int e = blockIdx.x * 256 + threadIdx.x;
    int s = ei32[e], d = ei32[EE + e];
    float w = ew[e];
    float dd = degd[d], ds = degs[s];
    float wfv = dd > 0.f ? w / dd : 0.f;
    float wbv = ds > 0.f ? w / ds : 0.f;
    atomicAdd(&temp[(size_t)d * NN + s], wfv);
    atomicAdd(&temp[(size_t)NN * NN + (size_t)s * NN + d], wbv);
}
__global__ void k_spconv(const float* __restrict__ temp, unsigned short* __restrict__ Mp) {
    size_t i0 = ((size_t)blockIdx.x * 256 + threadIdx.x) * 8;
    size_t dst = (i0 < (size_t)NN * NN) ? i0 : i0 + (size_t)NN * NN;
    unsigned short h8[8];
    #pragma unroll
    for (int j = 0; j < 8; j++) h8[j] = f2h(temp[i0 + j]);
    *(uint4*)(Mp + dst) = *(uint4*)h8;
}

__global__ void k_featd_h(const float* __restrict__ h, unsigned short* __restrict__ featd) {
    size_t idx = (size_t)blockIdx.x * 256 + threadIdx.x;
    size_t row = idx >> 6; int c = (int)(idx & 63);
    featd[row * DIN + c] = f2h(h[idx]);
}

__global__ void k_dec(const float* __restrict__ z, const float* __restrict__ W_dec,
                      const float* __restrict__ b_dec, float* __restrict__ out) {
    size_t idx = (size_t)blockIdx.x * 256 + threadIdx.x;
    size_t row = idx / ODIM; int o = (int)(idx % ODIM);
    const float* zr = z + row * HH;
    float acc = b_dec[o];
    for (int k = 0; k < HH; k++) acc += zr[k] * W_dec[k * ODIM + o];
    int b = (int)(row >> 10), n = (int)(row & 1023);
    int t = o >> 3, f = o & 7;
    out[(((size_t)b * TT + t) * NN + n) * FF + f] = acc;
}

extern "C" void kernel_launch(void* const* d_in, const int* in_sizes, int n_in,
                              void* d_out, int out_size, void* d_ws, size_t ws_size,
                              hipStream_t stream) {
    const float* x      = (const float*)d_in[0];
    const int*   eiraw  = (const int*)  d_in[1];
    const float* ew     = (const float*)d_in[2];
    const float* adj    = (const float*)d_in[3];
    const float* W_enc  = (const float*)d_in[4];
    const float* b_enc  = (const float*)d_in[5];
    const float* emb    = (const float*)d_in[6];
    const float* W_r    = (const float*)d_in[7];
    const float* b_r    = (const float*)d_in[8];
    const float* W_u    = (const float*)d_in[9];
    const float* b_u    = (const float*)d_in[10];
    const float* W_c    = (const float*)d_in[11];
    const float* b_c    = (const float*)d_in[12];
    const float* W_diff = (const float*)d_in[13];
    const float* b_diff = (const float*)d_in[14];
    const float* W_dec  = (const float*)d_in[15];
    const float* b_dec  = (const float*)d_in[16];

    // ---- workspace ~53 MiB ----
    unsigned short* Mf    = (unsigned short*)d_ws;            // 8 MiB
    unsigned short* Xh    = Mf + (size_t)4096 * NN;           // 2 MiB
    unsigned short* FD    = Xh + (size_t)BB * 64 * NN;        // 10 MiB: featd [16384][320]; Fh overlay
    unsigned short* Fh    = FD;                               //   [16384][256]
    unsigned short* featd = FD;
    float* h    = (float*)(FD + (size_t)BB * NN * DIN);       // 4 MiB
    float* z    = h;                                          // overlay
    float* ubuf = h + (size_t)BB * NN * HH;                   // 4 MiB
    unsigned short* AXall = (unsigned short*)(ubuf + (size_t)BB * NN * HH); // 12 MiB [tb][n][32]
    unsigned short* Mp    = AXall;                            // 8 MiB overlay (prep & readout)
    unsigned short* XallT = AXall + (size_t)192 * NN * 32;    // 3.125 MiB [1600][1024]
    unsigned short* Eg    = XallT + (size_t)1600 * NN;        // 0.5 MiB [4][1024][64]
    float* sptmp  = (float*)(Eg + (size_t)4 * NN * 64);       // 8 MiB
    float* constE = sptmp + (size_t)2 * NN * NN;              // 768 KiB [3][1024][64]
    float* Veg    = constE + (size_t)3 * NN * 64;             // 24 KiB [3][32][64]
    unsigned short* Wf_r = (unsigned short*)(Veg + 3 * 32 * 64);
    unsigned short* Wf_u = Wf_r + 4 * 9 * 512;
    unsigned short* Wf_c = Wf_u + 4 * 9 * 512;
    unsigned short* Wf_z = Wf_c + 4 * 9 * 512;                // 4*10*512
    float* rinv = (float*)(Wf_z + 4 * 10 * 512);
    float* cinv = rinv + NN;
    int*   eifl = (int*)(cinv + NN);
    int*   ei32 = eifl + 4;
    float* degd = (float*)(ei32 + 2 * EE);
    float* degs = degd + NN;

    hipMemsetAsync(h, 0, (size_t)BB * NN * HH * 4, stream);
    hipMemsetAsync(Xh, 0, (size_t)BB * 64 * NN * 2, stream);   // h = 0 at t=0

    // ---- build plain M = [Af; Af^2; Ab; Ab^2] (fp16), convert to fragment-major ----
    k_rowsum<<<NN, 256, 0, stream>>>(adj, rinv);
    k_colsum<<<NN / 256, 256, 0, stream>>>(adj, cinv);
    k_prepA<<<dim3(16, 16), 256, 0, stream>>>(adj, rinv, cinv, Mp);
    k_msq<<<dim3(16, 16, 2), 256, 0, stream>>>(Mp);
    k_m2frag<<<2048, 256, 0, stream>>>(Mp, Mf);

    // ---- x/emb transposes, batched x-hop (overwrites Mp region), const folds ----
    k_xT<<<TT * BB, 256, 0, stream>>>(x, XallT);
    k_embT<<<64, 256, 0, stream>>>(emb, XallT);
    k_hopX<<<dim3(32, 25), 256, 0, stream>>>(Mf, XallT, AXall, Eg);
    k_veg<<<24, 256, 0, stream>>>(W_enc, W_r, W_u, W_c, Veg);
    k_constE<<<dim3(256, 3), 256, 0, stream>>>(Eg, b_enc, W_r, W_u, W_c, constE);
    k_wfrag2<<<72, 256, 0, stream>>>(W_r, Veg, Wf_r);
    k_wfrag2<<<72, 256, 0, stream>>>(W_u, Veg + 2048, Wf_u);
    k_wfrag2<<<72, 256, 0, stream>>>(W_c, Veg + 4096, Wf_c);
    k_wfragL<<<80, 256, 0, stream>>>(W_diff, Wf_z);

    for (int t = 0; t < TT; t++) {
        const unsigned short* AXt = AXall + (size_t)t * BB * NN * 32;
        // 4 operators @ h -> Fh [row][g*64+c]
        k_hopA<<<dim3(32, 1, 16), 256, 0, stream>>>(Mf, Xh, Fh, 256, 64, 0);
        // gates: rh -> Xh (fp16), u -> ubuf (f32)
        k_gatesM<<<BB * NN / 64, 256, 0, stream>>>(AXt, Fh, Wf_r, Wf_u, b_r, b_u, constE, h, Xh, ubuf);
        // 4 operators @ rh -> Fh
        k_hopA<<<dim3(32, 1, 16), 256, 0, stream>>>(Mf, Xh, Fh, 256, 64, 0);
        // candidate + h update
        k_candM<<<BB * NN / 64, 256, 0, stream>>>(AXt, Fh, Wf_c, b_c, constE, ubuf, h, Xh);
    }

    // ---- DiffConv readout ----
    k_ei_detect<<<1, 256, 0, stream>>>(eiraw, eifl);
    k_ei_norm<<<2 * EE / 256, 256, 0, stream>>>(eiraw, eifl, ei32);
    hipMemsetAsync(degd, 0, (size_t)2 * NN * 4, stream);
    hipMemsetAsync(sptmp, 0, (size_t)2 * NN * NN * 4, stream);
    k_deg<<<EE / 256, 256, 0, stream>>>(ei32, ew, degd, degs);
    k_spadd<<<EE / 256, 256, 0, stream>>>(ei32, ew, degd, degs, sptmp);
    k_spconv<<<2 * NN * NN / (256 * 8), 256, 0, stream>>>(sptmp, Mp);
    k_msq<<<dim3(16, 16, 2), 256, 0, stream>>>(Mp);
    k_m2frag<<<2048, 256, 0, stream>>>(Mp, Mf);
    k_featd_h<<<BB * NN * HH / 256, 256, 0, stream>>>(h, featd);
    // [Sf;Sf2;Sb;Sb2] @ h (fp16 in Xh) -> featd cols 64 + g*64
    k_hopA<<<dim3(32, 1, 16), 256, 0, stream>>>(Mf, Xh, featd, DIN, 64, 64);
    k_zM<<<BB * NN / 64, 256, 0, stream>>>(featd, Wf_z, b_diff, z);
    k_dec<<<(BB * NN * ODIM) / 256, 256, 0, stream>>>(z, W_dec, b_dec, (float*)d_out);
}